// Round 7
// baseline (254.610 us; speedup 1.0000x reference)
//
#include <hip/hip_runtime.h>
#include <hip/hip_fp16.h>
#include <hip/hip_cooperative_groups.h>

// GCN, N=50000 nodes, E=800000 edges, 128->128(relu)->64, fp32 accum.
// CSR entries are 2B (src only).
// r17: r16 sliced passes REVERTED (FETCH stayed ~104MB, VALU overhead 4x:
//   aggs are at the random-gather fetch floor ~2.3TB/s on a uniform-random
//   graph -- no locality to mine; stop attacking gather traffic).
//   Structure cost attacked instead:
//   (a) H1 back to UNSCALED (GEMM independent of dis) -> 800K count
//       atomics interleave back INSIDE the gemm blocks (r12-proven),
//       hiding the count entirely; aggs use per-edge dis[src]*dis[v]
//       (r12-proven equal speed, same absmax).
//   (b) coop scan+fill with grid sized for the WIDEST phase (r13 lesson):
//       256 blocks x 1024; blocks 0-48 scan between grid.sync()s, ALL
//       blocks grid-stride the CSR fill at full machine width.
//   (c) dispatches 7 -> 5 (memset+W-prep in k_prep; count in gemm;
//       scan1+scan3+fill in one coop launch).
// r13 carry: 32-node gemm tiles (1563 blocks), LDS-assembled full-line
//   stores. r12 carry: swizzled fp16 W images, linear conflict-free W
//   staging, A-frags global->reg. NOTE (r10): degree-sorting bought ~0.

#define Nn 50000
#define Ne 800000
#define NE2 (Ne / 2)                  // 400000 int2 edge pairs
#define SCAN_B ((Nn + 1023) / 1024)   // 49 scan blocks
#define GT32 ((Nn + 31) / 32)         // 1563 gemm tiles (32 nodes)
#define COOP_B 256                    // coop grid (1 block/CU)

namespace cg = cooperative_groups;

using f16x8 = _Float16 __attribute__((ext_vector_type(8)));
using f32x4 = float __attribute__((ext_vector_type(4)));

// ---------------- prep: zero degi + build swizzled fp16 W images ----------------
// blocks 0..48: degi = 0. block 49: W1h. block 50: W2h.
// W?h layout: chunk (c, k8) = halves W[k8*8+j][c], j=0..7, stored at
//   halves offset c*128 + ((k8 ^ (c&7)) << 3). Readers XOR the same way;
//   stagers copy LINEARLY (swizzle baked into the global image).
__global__ __launch_bounds__(256) void k_prep(const float* __restrict__ W1,
                                              const float* __restrict__ W2,
                                              _Float16* __restrict__ W1h,
                                              _Float16* __restrict__ W2h,
                                              int* __restrict__ degi) {
  const int b = blockIdx.x, t = threadIdx.x;
  if (b < 49) {
    int i = b * 256 + t;
    if (i < Nn / 4) ((int4*)degi)[i] = make_int4(0, 0, 0, 0);
  } else if (b == 49) {
    // W1: fp32 [k=128][c=128] -> W1h 2048 chunks, 8 per thread
    for (int i = 0; i < 8; ++i) {
      int id = i * 256 + t;
      int c = id & 127, k8 = id >> 7;
      f16x8 hv;
      #pragma unroll
      for (int j = 0; j < 8; ++j) hv[j] = (_Float16)W1[(k8 * 8 + j) * 128 + c];
      *(f16x8*)&W1h[c * 128 + ((k8 ^ (c & 7)) << 3)] = hv;
    }
  } else {
    // W2: fp32 [k=128][c=64] -> W2h 1024 chunks, 4 per thread
    for (int i = 0; i < 4; ++i) {
      int id = i * 256 + t;
      int c = id & 63, k8 = id >> 6;
      f16x8 hv;
      #pragma unroll
      for (int j = 0; j < 8; ++j) hv[j] = (_Float16)W2[(k8 * 8 + j) * 64 + c];
      *(f16x8*)&W2h[c * 128 + ((k8 ^ (c & 7)) << 3)] = hv;
    }
  }
}

// ---------------- FUSED: layer-1 MFMA GEMM (32-node tile) + degree count ----------------
// Per block: (1) linear-stage W1h -> LDS (32KB, conflict-free);
// (2) count 256 int2 edges (atomics hide under staging/X-load latency);
// (3) A-frags direct global->reg; (4) MFMA; (5) acc -> LDS (aliases Wts
//     post-barrier) -> contiguous f16x8 stores (full lines). H1 UNSCALED.
// Wave w: rows [(w&1)*16, +16), cols [(w>>1)*64, +64).
__global__ __launch_bounds__(256, 5) void k_gemm32_count(
    const float* __restrict__ X, const _Float16* __restrict__ W1h,
    __half* __restrict__ H, const int2* __restrict__ col2,
    int* __restrict__ degi, ushort2* __restrict__ rank2) {
  __shared__ _Float16 Wts[128 * 128];   // 32 KB swizzled W image; reused for out
  _Float16* Hsx = Wts;                  // [32][136] fp16 out tile (8.7 KB)

  const int tid = threadIdx.x;
  const int base = blockIdx.x * 32;

  // stage W1h -> LDS: 2048 x 16B chunks, 8 per thread, fully coalesced
  {
    const f16x8* src = (const f16x8*)W1h;
    f16x8* dst = (f16x8*)Wts;
    #pragma unroll
    for (int i = 0; i < 8; ++i) dst[i * 256 + tid] = src[i * 256 + tid];
  }

  // edge-count slice: 1 int2 per thread; latency hides under staging
  {
    int i0 = blockIdx.x * 256 + tid;
    if (i0 < NE2) {
      int2 c = col2[i0];
      ushort2 rk;
      rk.x = (unsigned short)atomicAdd(&degi[c.x], 1);
      rk.y = (unsigned short)atomicAdd(&degi[c.y], 1);
      rank2[i0] = rk;
    }
  }

  // A-fragments direct from global X
  const int w = tid >> 6, lane = tid & 63;
  const int quad = lane >> 4, mrow = lane & 15;
  const int rbase = (w & 1) * 16, cbase = (w >> 1) * 64;
  int anode = base + rbase + mrow;
  if (anode >= Nn) anode = Nn - 1;
  const float4* xg = (const float4*)(X + (size_t)anode * 128);
  f16x8 av[4];
  #pragma unroll
  for (int ko = 0; ko < 4; ++ko) {
    float4 x0 = xg[ko * 8 + quad * 2];
    float4 x1 = xg[ko * 8 + quad * 2 + 1];
    av[ko][0] = (_Float16)x0.x; av[ko][1] = (_Float16)x0.y;
    av[ko][2] = (_Float16)x0.z; av[ko][3] = (_Float16)x0.w;
    av[ko][4] = (_Float16)x1.x; av[ko][5] = (_Float16)x1.y;
    av[ko][6] = (_Float16)x1.z; av[ko][7] = (_Float16)x1.w;
  }
  __syncthreads();

  f32x4 acc[4];
  #pragma unroll
  for (int ct = 0; ct < 4; ++ct) acc[ct] = (f32x4){0.f, 0.f, 0.f, 0.f};

  #pragma unroll
  for (int ko = 0; ko < 4; ++ko) {
    #pragma unroll
    for (int ct = 0; ct < 4; ++ct) {
      int c = cbase + ct * 16 + mrow;
      f16x8 bv = *(const f16x8*)&Wts[c * 128 + (((ko * 4 + quad) ^ (c & 7)) << 3)];
      acc[ct] = __builtin_amdgcn_mfma_f32_16x16x32_f16(av[ko], bv, acc[ct], 0, 0, 0);
    }
  }

  __syncthreads();   // all waves done reading Wts; safe to alias
  #pragma unroll
  for (int ct = 0; ct < 4; ++ct) {
    #pragma unroll
    for (int r = 0; r < 4; ++r)
      Hsx[(rbase + quad * 4 + r) * 136 + cbase + ct * 16 + mrow] =
          (_Float16)acc[ct][r];
  }
  __syncthreads();

  // contiguous stores: 512 f16x8 chunks (32 rows x 16), 2 per thread
  #pragma unroll
  for (int i = 0; i < 2; ++i) {
    int id = i * 256 + tid;
    int r = id >> 4, ch = id & 15;
    int node = base + r;
    if (node < Nn)
      *(f16x8*)((_Float16*)H + (size_t)node * 128 + ch * 8) =
          *(const f16x8*)&Hsx[r * 136 + ch * 8];
  }
}

// ---------------- cooperative: scan (blocks 0-48) + CSR fill (ALL blocks) ----------------
// 256 blocks x 1024 (1 block/CU, co-resident). Scan phases use blocks
// 0..48; fill grid-strides 400K int2 across all 262144 threads (r13 lesson:
// size the coop grid for the WIDEST phase).
__global__ __launch_bounds__(1024) void k_scanfill(
    const int* __restrict__ degi, int* __restrict__ rowptr,
    float* __restrict__ dis, int* __restrict__ bsum,
    const int2* __restrict__ row2, const int2* __restrict__ col2,
    const ushort2* __restrict__ rank2, unsigned short* __restrict__ csr) {
  cg::grid_group grid = cg::this_grid();
  __shared__ int wsum[16];
  __shared__ int off_s;
  const int tid = threadIdx.x;
  const int bid = blockIdx.x;
  const int lane = tid & 63, wid = tid >> 6;
  const int i = bid * 1024 + tid;
  int local = 0, v = 0;

  // ---- phase 1 (blocks 0-48): block-local exclusive scan + dis ----
  if (bid < SCAN_B) {
    v = (i < Nn) ? degi[i] : 0;
    if (i < Nn) dis[i] = rsqrtf((float)(v + 1));   // self-loop adds 1
    int incl = v;
    #pragma unroll
    for (int off = 1; off < 64; off <<= 1) {
      int t = __shfl_up(incl, off);
      if (lane >= off) incl += t;
    }
    if (lane == 63) wsum[wid] = incl;
    __syncthreads();
    if (wid == 0) {
      int wv = (lane < 16) ? wsum[lane] : 0;
      #pragma unroll
      for (int off = 1; off < 16; off <<= 1) {
        int t = __shfl_up(wv, off);
        if (lane >= off) wv += t;
      }
      if (lane < 16) wsum[lane] = wv;  // inclusive over wave totals
    }
    __syncthreads();
    int woff = (wid > 0) ? wsum[wid - 1] : 0;
    local = woff + incl - v;                     // block-local exclusive
    if (tid == 0) bsum[bid] = wsum[15];          // block total
  }
  grid.sync();

  // ---- phase 2 (blocks 0-48): scan the 49 block sums, add offset ----
  if (bid < SCAN_B) {
    if (tid < 64) {
      int bv = (tid < SCAN_B) ? bsum[tid] : 0;
      int binc = bv;
      #pragma unroll
      for (int off = 1; off < 64; off <<= 1) {
        int t = __shfl_up(binc, off);
        if (tid >= off) binc += t;
      }
      if (tid == bid) off_s = binc - bv;                        // exclusive
      if (bid == 0 && tid == SCAN_B - 1) rowptr[Nn] = binc;     // == Ne
    }
    __syncthreads();
    if (i < Nn) rowptr[i] = local + off_s;
  }
  grid.sync();

  // ---- phase 3 (ALL blocks): CSR fill, grid-stride over int2 pairs ----
  for (int t = bid * 1024 + tid; t < NE2; t += COOP_B * 1024) {
    int2 r = row2[t];
    int2 c = col2[t];
    ushort2 k = rank2[t];
    csr[rowptr[c.x] + (int)k.x] = (unsigned short)r.x;
    csr[rowptr[c.y] + (int)k.y] = (unsigned short)r.y;
  }
}

__device__ __forceinline__ float2 h2f(unsigned int u) {
  return __half22float2(*(const __half2*)&u);
}

// ---------------- FUSED: agg128(+b1, relu) -> LDS fp16 -> MFMA @ W2 -> H2 fp16 ----------------
// Stage A: 4 nodes/wave, 16 lanes/node, uint4 (8 fp16 feats)/lane,
//   per-edge w = dis[src]*dis[v]; self w = dis[v]^2. D=6 gathers in
//   flight + batch-ahead csr prefetch. Stage B: 16x64 MFMA vs swizzled
//   W2 image; H2 raw (unscaled); LDS-assembled contiguous stores.
// Nn = 50000 = 3125 * 16 exactly -> no partial blocks.
__global__ __launch_bounds__(256) void k_agg128_gemm64(
    const __half* __restrict__ H, const unsigned short* __restrict__ csr,
    const int* __restrict__ rowptr, const float* __restrict__ dis,
    const float* __restrict__ bias, const _Float16* __restrict__ W2h,
    __half* __restrict__ H2, int n) {
  __shared__ _Float16 Wts[64 * 128];   // swizzled W2 image (16KB, linear copy)
  __shared__ _Float16 Hs[16 * 136];    // 16 aggregated rows; reused for out

  const int tid = threadIdx.x;
  const int wid = tid >> 6, lane = tid & 63;
  const int sub = lane >> 4, fl = lane & 15;
  const int nb = wid * 4 + sub;                  // node-in-block [0,16)
  const int v = blockIdx.x * 16 + nb;

  // stage W2h -> LDS: 1024 x 16B chunks, linear, conflict-free
  {
    const f16x8* src = (const f16x8*)W2h;
    f16x8* dst = (f16x8*)Wts;
    #pragma unroll
    for (int i = 0; i < 4; ++i) dst[i * 256 + tid] = src[i * 256 + tid];
  }

  // ---- stage A: weighted sum of H1 rows ----
  int s = rowptr[v], e = rowptr[v + 1];
  float d = dis[v];
  float sw = d * d;                              // self-loop norm = 1/deg
  const uint4* Hq = (const uint4*)H;             // 16 uint4 per 256B row
  uint4 hv = Hq[(size_t)v * 16 + fl];
  float2 p0 = h2f(hv.x), p1 = h2f(hv.y), p2 = h2f(hv.z), p3 = h2f(hv.w);
  float a0 = p0.x * sw, a1 = p0.y * sw, a2 = p1.x * sw, a3 = p1.y * sw;
  float a4 = p2.x * sw, a5 = p2.y * sw, a6 = p3.x * sw, a7 = p3.y * sw;
  constexpr int D = 6;
  if (s < e) {
    int srcs[D];
    #pragma unroll
    for (int j = 0; j < D; ++j) {
      int idx = s + j;
      srcs[j] = csr[(idx < e) ? idx : (e - 1)];
    }
    int base = s;
    for (; base + D <= e; base += D) {           // full batches
      uint4 q[D];
      float wd[D];
      #pragma unroll
      for (int j = 0; j < D; ++j) q[j] = Hq[(size_t)srcs[j] * 16 + fl];
      #pragma unroll
      for (int j = 0; j < D; ++j) wd[j] = dis[srcs[j]];
      int ns[D];                                 // prefetch next batch srcs
      #pragma unroll
      for (int j = 0; j < D; ++j) {
        int idx = base + D + j;
        ns[j] = csr[(idx < e) ? idx : (e - 1)];
      }
      #pragma unroll
      for (int j = 0; j < D; ++j) {
        float w = wd[j] * d;
        float2 t;
        t = h2f(q[j].x); a0 = fmaf(w, t.x, a0); a1 = fmaf(w, t.y, a1);
        t = h2f(q[j].y); a2 = fmaf(w, t.x, a2); a3 = fmaf(w, t.y, a3);
        t = h2f(q[j].z); a4 = fmaf(w, t.x, a4); a5 = fmaf(w, t.y, a5);
        t = h2f(q[j].w); a6 = fmaf(w, t.x, a6); a7 = fmaf(w, t.y, a7);
      }
      #pragma unroll
      for (int j = 0; j < D; ++j) srcs[j] = ns[j];
    }
    if (base < e) {                              // masked tail batch
      uint4 q[D];
      float wd[D];
      #pragma unroll
      for (int j = 0; j < D; ++j) q[j] = Hq[(size_t)srcs[j] * 16 + fl];
      #pragma unroll
      for (int j = 0; j < D; ++j) wd[j] = dis[srcs[j]];
      #pragma unroll
      for (int j = 0; j < D; ++j) {
        float w = (base + j < e) ? wd[j] * d : 0.f;
        float2 t;
        t = h2f(q[j].x); a0 = fmaf(w, t.x, a0); a1 = fmaf(w, t.y, a1);
        t = h2f(q[j].y); a2 = fmaf(w, t.x, a2); a3 = fmaf(w, t.y, a3);
        t = h2f(q[j].z); a4 = fmaf(w, t.x, a4); a5 = fmaf(w, t.y, a5);
        t = h2f(q[j].w); a6 = fmaf(w, t.x, a6); a7 = fmaf(w, t.y, a7);
      }
    }
  }
  // +b1, relu, fp16 -> LDS row nb
  {
    const float4* Bq = (const float4*)bias;
    float4 b0 = Bq[fl * 2], b1v = Bq[fl * 2 + 1];
    f16x8 hrow;
    hrow[0] = (_Float16)fmaxf(a0 + b0.x, 0.f);
    hrow[1] = (_Float16)fmaxf(a1 + b0.y, 0.f);
    hrow[2] = (_Float16)fmaxf(a2 + b0.z, 0.f);
    hrow[3] = (_Float16)fmaxf(a3 + b0.w, 0.f);
    hrow[4] = (_Float16)fmaxf(a4 + b1v.x, 0.f);
    hrow[5] = (_Float16)fmaxf(a5 + b1v.y, 0.f);
    hrow[6] = (_Float16)fmaxf(a6 + b1v.z, 0.f);
    hrow[7] = (_Float16)fmaxf(a7 + b1v.w, 0.f);
    *(f16x8*)&Hs[nb * 136 + fl * 8] = hrow;
  }
  __syncthreads();

  // ---- stage B: 16x64 = (16x128) @ (128x64), wave w -> cols [w*16, +16) ----
  const int quad = lane >> 4, mrow = lane & 15;
  f32x4 acc = (f32x4){0.f, 0.f, 0.f, 0.f};
  const int c = wid * 16 + mrow;
  #pragma unroll
  for (int ko = 0; ko < 4; ++ko) {
    f16x8 avx = *(const f16x8*)&Hs[mrow * 136 + ko * 32 + quad * 8];
    f16x8 bv = *(const f16x8*)&Wts[c * 128 + (((ko * 4 + quad) ^ (c & 7)) << 3)];
    acc = __builtin_amdgcn_mfma_f32_16x16x32_f16(avx, bv, acc, 0, 0, 0);
  }

  __syncthreads();   // all waves done reading Hs; safe to alias
  #pragma unroll
  for (int r = 0; r < 4; ++r)
    Hs[(quad * 4 + r) * 136 + wid * 16 + mrow] = (_Float16)acc[r];
  __syncthreads();

  // contiguous stores: 128 f16x8 chunks (16 rows x 8), threads 0..127
  if (tid < 128) {
    int r = tid >> 3, ch = tid & 7;
    *(f16x8*)((_Float16*)H2 + ((size_t)blockIdx.x * 16 + r) * 64 + ch * 8) =
        *(const f16x8*)&Hs[r * 136 + ch * 8];
  }
}

// ---------------- aggregate 64 feats (+bias): per-edge dis norm ----------------
// 4 nodes/wave, 16 lanes/node, uint2 (4 feats)/lane; D=8 batches,
// batch-ahead csr prefetch.
__global__ __launch_bounds__(256) void k_agg64(const __half* __restrict__ H,
                                               const unsigned short* __restrict__ csr,
                                               const int* __restrict__ rowptr,
                                               const float* __restrict__ dis,
                                               const float* __restrict__ bias,
                                               float* __restrict__ Out, int n) {
  const int wid = threadIdx.x >> 6, lane = threadIdx.x & 63;
  const int sub = lane >> 4, fl = lane & 15;
  int v = blockIdx.x * 16 + wid * 4 + sub;
  if (v >= n) return;
  int s = rowptr[v], e = rowptr[v + 1];
  float d = dis[v];
  float sw = d * d;
  const uint2* Hq = (const uint2*)H;             // 16 uint2 per 128B row
  uint2 hv = Hq[(size_t)v * 16 + fl];
  float2 p0 = h2f(hv.x), p1 = h2f(hv.y);
  float a0 = p0.x * sw, a1 = p0.y * sw, a2 = p1.x * sw, a3 = p1.y * sw;
  constexpr int D = 8;
  if (s < e) {
    int srcs[D];
    #pragma unroll
    for (int j = 0; j < D; ++j) {
      int idx = s + j;
      srcs[j] = csr[(idx < e) ? idx : (e - 1)];
    }
    int base = s;
    for (; base + D <= e; base += D) {           // full batches
      uint2 q[D];
      float wd[D];
      #pragma unroll
      for (int j = 0; j < D; ++j) q[j] = Hq[(size_t)srcs[j] * 16 + fl];
      #pragma unroll
      for (int j = 0; j < D; ++j) wd[j] = dis[srcs[j]];
      int ns[D];                                 // prefetch next batch srcs
      #pragma unroll
      for (int j = 0; j < D; ++j) {
        int idx = base + D + j;
        ns[j] = csr[(idx < e) ? idx : (e - 1)];
      }
      #pragma unroll
      for (int j = 0; j < D; ++j) {
        float w = wd[j] * d;
        float2 t;
        t = h2f(q[j].x); a0 = fmaf(w, t.x, a0); a1 = fmaf(w, t.y, a1);
        t = h2f(q[j].y); a2 = fmaf(w, t.x, a2); a3 = fmaf(w, t.y, a3);
      }
      #pragma unroll
      for (int j = 0; j < D; ++j) srcs[j] = ns[j];
    }
    if (base < e) {                              // masked tail batch
      uint2 q[D];
      float wd[D];
      #pragma unroll
      for (int j = 0; j < D; ++j) q[j] = Hq[(size_t)srcs[j] * 16 + fl];
      #pragma unroll
      for (int j = 0; j < D; ++j) wd[j] = dis[srcs[j]];
      #pragma unroll
      for (int j = 0; j < D; ++j) {
        float w = (base + j < e) ? wd[j] * d : 0.f;
        float2 t;
        t = h2f(q[j].x); a0 = fmaf(w, t.x, a0); a1 = fmaf(w, t.y, a1);
        t = h2f(q[j].y); a2 = fmaf(w, t.x, a2); a3 = fmaf(w, t.y, a3);
      }
    }
  }
  const float4* Bq = (const float4*)bias;
  float4 b = Bq[fl];
  float4 o = make_float4(a0 + b.x, a1 + b.y, a2 + b.z, a3 + b.w);
  ((float4*)(Out + (size_t)v * 64))[fl] = o;
}

extern "C" void kernel_launch(void* const* d_in, const int* in_sizes, int n_in,
                              void* d_out, int out_size, void* d_ws, size_t ws_size,
                              hipStream_t stream) {
  const float* x  = (const float*)d_in[0];
  const int*   ei = (const int*)d_in[1];    // [2, E] row-major
  const int*   row = ei;                    // edge_index[0] (source)
  const int*   col = ei + Ne;               // edge_index[1] (dest / segment)
  const float* W1 = (const float*)d_in[2];
  const float* b1 = (const float*)d_in[3];
  const float* W2 = (const float*)d_in[4];
  const float* b2 = (const float*)d_in[5];
  float* out = (float*)d_out;

  char* ws = (char*)d_ws;
  size_t off = 0;
  auto alloc = [&](size_t bytes) -> void* {
    void* p = ws + off;
    off += (bytes + 255) & ~(size_t)255;
    return p;
  };
  int*    degi   = (int*)   alloc(Nn * sizeof(int));       // zeroed by k_prep
  int*    rowptr = (int*)   alloc((Nn + 1) * sizeof(int));
  float*  dis    = (float*) alloc(Nn * sizeof(float));
  int*    bsum   = (int*)   alloc(64 * sizeof(int));
  unsigned short* rank = (unsigned short*)alloc((size_t)Ne * sizeof(unsigned short)); // 1.6 MB
  unsigned short* csr  = (unsigned short*)alloc((size_t)Ne * sizeof(unsigned short)); // 1.6 MB
  __half* H1     = (__half*)alloc((size_t)Nn * 128 * sizeof(__half));  // 12.8 MB (unscaled)
  __half* H2     = (__half*)alloc((size_t)Nn * 64 * sizeof(__half));   // 6.4 MB (unscaled)
  _Float16* W1h  = (_Float16*)alloc(128 * 128 * sizeof(_Float16));     // 32 KB
  _Float16* W2h  = (_Float16*)alloc(64 * 128 * sizeof(_Float16));      // 16 KB

  const int NGB = (Nn + 15) / 16;           // 3125 agg blocks (16 nodes each)

  // 1) prep: degi=0 + swizzled fp16 W images (replaces memset)
  k_prep<<<51, 256, 0, stream>>>(W1, W2, W1h, W2h, degi);
  // 2) fused: H1 = fp16(x@W1) + degree count (hidden under GEMM)
  k_gemm32_count<<<GT32, 256, 0, stream>>>(x, W1h, H1, (const int2*)col,
                                           degi, (ushort2*)rank);
  // 3) cooperative: scan (49 blocks) + CSR fill (all 256 blocks)
  {
    const int2* row2 = (const int2*)row;
    const int2* col2 = (const int2*)col;
    ushort2* rank2 = (ushort2*)rank;
    void* args[] = {(void*)&degi, (void*)&rowptr, (void*)&dis, (void*)&bsum,
                    (void*)&row2, (void*)&col2, (void*)&rank2, (void*)&csr};
    hipLaunchCooperativeKernel((void*)k_scanfill, dim3(COOP_B), dim3(1024),
                               args, 0, stream);
  }
  // 4) fused: H2 = fp16( relu(agg(H1) + b1) @ W2 )
  k_agg128_gemm64<<<NGB, 256, 0, stream>>>(H1, csr, rowptr, dis, b1, W2h, H2, Nn);
  // 5) layer 2: out = agg(H2) + b2
  k_agg64<<<NGB, 256, 0, stream>>>(H2, csr, rowptr, dis, b2, out, Nn);
}

// Round 8
// 181.893 us; speedup vs baseline: 1.3998x; 1.3998x over previous
//
#include <hip/hip_runtime.h>
#include <hip/hip_fp16.h>

// GCN, N=50000 nodes, E=800000 edges, 128->128(relu)->64, fp32 accum.
// CSR entries are 2B (src only).
// r18: coop kernel PERMANENTLY banned (r13+r17: grid.sync costs ~25us each
//   on MI355X -- 58us scanfill was width-INDEPENDENT, i.e. sync+launch
//   overhead, not fill). Back to the proven r12/r14 component set, with
//   ONE new structural cut: scan1+scan3 merged into a single-dispatch
//   DECOUPLED-LOOKBACK scan (49 blocks; each publishes its block total
//   with a READY bit via atomicExch, wave 0 parallel-polls predecessors
//   with device-scope atomic reads; all 49 blocks co-resident -> no
//   deadlock, no grid.sync). Chain: prep -> gemm+count -> scan_lb ->
//   fill -> agg128 -> agg64 (6 dispatches).
// r17 carry: H1 unscaled -> count atomics hidden inside GEMM; per-edge
//   dis[src]*dis[v] in aggs (r12-proven). r13 carry: 32-node gemm tiles,
//   LDS-assembled full-line stores. r12 carry: swizzled fp16 W images,
//   linear conflict-free W staging, A-frags global->reg, standalone fill.
// NOTE (r10): degree-sorting bought ~0. (r16): aggs at random-gather
//   fetch floor (~104MB L2-miss traffic @ ~2.3TB/s); slicing nulled.

#define Nn 50000
#define Ne 800000
#define NE2 (Ne / 2)                  // 400000 int2 edge pairs
#define SCAN_B ((Nn + 1023) / 1024)   // 49 scan blocks
#define GT32 ((Nn + 31) / 32)         // 1563 gemm tiles (32 nodes)
#define E1B ((NE2 + 255) / 256)       // 1563 fill blocks (1 int2/thread)
#define READY (1 << 30)

using f16x8 = _Float16 __attribute__((ext_vector_type(8)));
using f32x4 = float __attribute__((ext_vector_type(4)));

// ---------------- prep: zero degi+bstate + build swizzled fp16 W images ----------------
// blocks 0..48: degi = 0 (block 0 also zeroes bstate). 49: W1h. 50: W2h.
// W?h layout: chunk (c, k8) = halves W[k8*8+j][c], j=0..7, stored at
//   halves offset c*128 + ((k8 ^ (c&7)) << 3). Readers XOR the same way;
//   stagers copy LINEARLY (swizzle baked into the global image).
__global__ __launch_bounds__(256) void k_prep(const float* __restrict__ W1,
                                              const float* __restrict__ W2,
                                              _Float16* __restrict__ W1h,
                                              _Float16* __restrict__ W2h,
                                              int* __restrict__ degi,
                                              int* __restrict__ bstate) {
  const int b = blockIdx.x, t = threadIdx.x;
  if (b < 49) {
    int i = b * 256 + t;
    if (i < Nn / 4) ((int4*)degi)[i] = make_int4(0, 0, 0, 0);
    if (b == 0 && t < 64) bstate[t] = 0;
  } else if (b == 49) {
    // W1: fp32 [k=128][c=128] -> W1h 2048 chunks, 8 per thread
    for (int i = 0; i < 8; ++i) {
      int id = i * 256 + t;
      int c = id & 127, k8 = id >> 7;
      f16x8 hv;
      #pragma unroll
      for (int j = 0; j < 8; ++j) hv[j] = (_Float16)W1[(k8 * 8 + j) * 128 + c];
      *(f16x8*)&W1h[c * 128 + ((k8 ^ (c & 7)) << 3)] = hv;
    }
  } else {
    // W2: fp32 [k=128][c=64] -> W2h 1024 chunks, 4 per thread
    for (int i = 0; i < 4; ++i) {
      int id = i * 256 + t;
      int c = id & 63, k8 = id >> 6;
      f16x8 hv;
      #pragma unroll
      for (int j = 0; j < 8; ++j) hv[j] = (_Float16)W2[(k8 * 8 + j) * 64 + c];
      *(f16x8*)&W2h[c * 128 + ((k8 ^ (c & 7)) << 3)] = hv;
    }
  }
}

// ---------------- FUSED: layer-1 MFMA GEMM (32-node tile) + degree count ----------------
// Per block: (1) linear-stage W1h -> LDS (32KB, conflict-free);
// (2) count 256 int2 edges (atomics hide under staging/X-load latency);
// (3) A-frags direct global->reg; (4) MFMA; (5) acc -> LDS (aliases Wts
//     post-barrier) -> contiguous f16x8 stores (full lines). H1 UNSCALED.
// Wave w: rows [(w&1)*16, +16), cols [(w>>1)*64, +64).
__global__ __launch_bounds__(256, 5) void k_gemm32_count(
    const float* __restrict__ X, const _Float16* __restrict__ W1h,
    __half* __restrict__ H, const int2* __restrict__ col2,
    int* __restrict__ degi, ushort2* __restrict__ rank2) {
  __shared__ _Float16 Wts[128 * 128];   // 32 KB swizzled W image; reused for out
  _Float16* Hsx = Wts;                  // [32][136] fp16 out tile (8.7 KB)

  const int tid = threadIdx.x;
  const int base = blockIdx.x * 32;

  // stage W1h -> LDS: 2048 x 16B chunks, 8 per thread, fully coalesced
  {
    const f16x8* src = (const f16x8*)W1h;
    f16x8* dst = (f16x8*)Wts;
    #pragma unroll
    for (int i = 0; i < 8; ++i) dst[i * 256 + tid] = src[i * 256 + tid];
  }

  // edge-count slice: 1 int2 per thread; latency hides under staging
  {
    int i0 = blockIdx.x * 256 + tid;
    if (i0 < NE2) {
      int2 c = col2[i0];
      ushort2 rk;
      rk.x = (unsigned short)atomicAdd(&degi[c.x], 1);
      rk.y = (unsigned short)atomicAdd(&degi[c.y], 1);
      rank2[i0] = rk;
    }
  }

  // A-fragments direct from global X
  const int w = tid >> 6, lane = tid & 63;
  const int quad = lane >> 4, mrow = lane & 15;
  const int rbase = (w & 1) * 16, cbase = (w >> 1) * 64;
  int anode = base + rbase + mrow;
  if (anode >= Nn) anode = Nn - 1;
  const float4* xg = (const float4*)(X + (size_t)anode * 128);
  f16x8 av[4];
  #pragma unroll
  for (int ko = 0; ko < 4; ++ko) {
    float4 x0 = xg[ko * 8 + quad * 2];
    float4 x1 = xg[ko * 8 + quad * 2 + 1];
    av[ko][0] = (_Float16)x0.x; av[ko][1] = (_Float16)x0.y;
    av[ko][2] = (_Float16)x0.z; av[ko][3] = (_Float16)x0.w;
    av[ko][4] = (_Float16)x1.x; av[ko][5] = (_Float16)x1.y;
    av[ko][6] = (_Float16)x1.z; av[ko][7] = (_Float16)x1.w;
  }
  __syncthreads();

  f32x4 acc[4];
  #pragma unroll
  for (int ct = 0; ct < 4; ++ct) acc[ct] = (f32x4){0.f, 0.f, 0.f, 0.f};

  #pragma unroll
  for (int ko = 0; ko < 4; ++ko) {
    #pragma unroll
    for (int ct = 0; ct < 4; ++ct) {
      int c = cbase + ct * 16 + mrow;
      f16x8 bv = *(const f16x8*)&Wts[c * 128 + (((ko * 4 + quad) ^ (c & 7)) << 3)];
      acc[ct] = __builtin_amdgcn_mfma_f32_16x16x32_f16(av[ko], bv, acc[ct], 0, 0, 0);
    }
  }

  __syncthreads();   // all waves done reading Wts; safe to alias
  #pragma unroll
  for (int ct = 0; ct < 4; ++ct) {
    #pragma unroll
    for (int r = 0; r < 4; ++r)
      Hsx[(rbase + quad * 4 + r) * 136 + cbase + ct * 16 + mrow] =
          (_Float16)acc[ct][r];
  }
  __syncthreads();

  // contiguous stores: 512 f16x8 chunks (32 rows x 16), 2 per thread
  #pragma unroll
  for (int i = 0; i < 2; ++i) {
    int id = i * 256 + tid;
    int r = id >> 4, ch = id & 15;
    int node = base + r;
    if (node < Nn)
      *(f16x8*)((_Float16*)H + (size_t)node * 128 + ch * 8) =
          *(const f16x8*)&Hsx[r * 136 + ch * 8];
  }
}

// ---------------- single-dispatch scan: decoupled lookback (NO grid.sync) ----------------
// 49 blocks x 1024. Each block: local exclusive scan of degi + dis;
// publish block total via atomicExch(total|READY); wave 0 parallel-polls
// all predecessors' totals (device-scope atomic reads), reduces, adds.
// All 49 blocks co-resident on 256 CUs -> no deadlock.
__global__ __launch_bounds__(1024) void k_scan_lb(const int* __restrict__ degi,
                                                  int* __restrict__ rowptr,
                                                  float* __restrict__ dis,
                                                  int* __restrict__ bstate) {
  __shared__ int wsum[16];
  __shared__ int off_s;
  const int tid = threadIdx.x;
  const int bid = blockIdx.x;
  const int lane = tid & 63, wid = tid >> 6;
  const int i = bid * 1024 + tid;

  int v = (i < Nn) ? degi[i] : 0;
  if (i < Nn) dis[i] = rsqrtf((float)(v + 1));   // self-loop adds 1
  int incl = v;
  #pragma unroll
  for (int off = 1; off < 64; off <<= 1) {
    int t = __shfl_up(incl, off);
    if (lane >= off) incl += t;
  }
  if (lane == 63) wsum[wid] = incl;
  __syncthreads();
  if (wid == 0) {
    int wv = (lane < 16) ? wsum[lane] : 0;
    #pragma unroll
    for (int off = 1; off < 16; off <<= 1) {
      int t = __shfl_up(wv, off);
      if (lane >= off) wv += t;
    }
    if (lane < 16) wsum[lane] = wv;  // inclusive over wave totals
    if (lane == 15) atomicExch(&bstate[bid], wv | READY);  // publish total
  }
  __syncthreads();
  // lookback: wave 0 polls predecessors in parallel (lane j covers block j)
  if (wid == 0) {
    int sum = 0;
    if (lane < bid) {
      int bv;
      do { bv = atomicAdd(&bstate[lane], 0); } while (!(bv & READY));
      sum = bv & ~READY;
    }
    #pragma unroll
    for (int off = 32; off >= 1; off >>= 1) sum += __shfl_xor(sum, off);
    if (lane == 0) off_s = sum;
  }
  __syncthreads();
  int woff = (wid > 0) ? wsum[wid - 1] : 0;
  if (i <= Nn) rowptr[i] = off_s + woff + incl - v;   // global exclusive
}

// ---------------- CSR fill: 2B src only, no atomic (1 int2/thread) ----------------
__global__ __launch_bounds__(256) void k_fill(const int2* __restrict__ row2,
                                              const int2* __restrict__ col2,
                                              const int* __restrict__ rowptr,
                                              const ushort2* __restrict__ rank2,
                                              unsigned short* __restrict__ csr) {
  int t = blockIdx.x * 256 + threadIdx.x;
  if (t >= NE2) return;
  int2 r = row2[t];
  int2 c = col2[t];
  ushort2 k = rank2[t];
  csr[rowptr[c.x] + (int)k.x] = (unsigned short)r.x;
  csr[rowptr[c.y] + (int)k.y] = (unsigned short)r.y;
}

__device__ __forceinline__ float2 h2f(unsigned int u) {
  return __half22float2(*(const __half2*)&u);
}

// ---------------- FUSED: agg128(+b1, relu) -> LDS fp16 -> MFMA @ W2 -> H2 fp16 ----------------
// Stage A: 4 nodes/wave, 16 lanes/node, uint4 (8 fp16 feats)/lane,
//   per-edge w = dis[src]*dis[v]; self w = dis[v]^2. D=6 gathers in
//   flight + batch-ahead csr prefetch. Stage B: 16x64 MFMA vs swizzled
//   W2 image; LDS-assembled contiguous stores.
// Nn = 50000 = 3125 * 16 exactly -> no partial blocks.
__global__ __launch_bounds__(256) void k_agg128_gemm64(
    const __half* __restrict__ H, const unsigned short* __restrict__ csr,
    const int* __restrict__ rowptr, const float* __restrict__ dis,
    const float* __restrict__ bias, const _Float16* __restrict__ W2h,
    __half* __restrict__ H2, int n) {
  __shared__ _Float16 Wts[64 * 128];   // swizzled W2 image (16KB, linear copy)
  __shared__ _Float16 Hs[16 * 136];    // 16 aggregated rows; reused for out

  const int tid = threadIdx.x;
  const int wid = tid >> 6, lane = tid & 63;
  const int sub = lane >> 4, fl = lane & 15;
  const int nb = wid * 4 + sub;                  // node-in-block [0,16)
  const int v = blockIdx.x * 16 + nb;

  // stage W2h -> LDS: 1024 x 16B chunks, linear, conflict-free
  {
    const f16x8* src = (const f16x8*)W2h;
    f16x8* dst = (f16x8*)Wts;
    #pragma unroll
    for (int i = 0; i < 4; ++i) dst[i * 256 + tid] = src[i * 256 + tid];
  }

  // ---- stage A: weighted sum of H1 rows ----
  int s = rowptr[v], e = rowptr[v + 1];
  float d = dis[v];
  float sw = d * d;                              // self-loop norm = 1/deg
  const uint4* Hq = (const uint4*)H;             // 16 uint4 per 256B row
  uint4 hv = Hq[(size_t)v * 16 + fl];
  float2 p0 = h2f(hv.x), p1 = h2f(hv.y), p2 = h2f(hv.z), p3 = h2f(hv.w);
  float a0 = p0.x * sw, a1 = p0.y * sw, a2 = p1.x * sw, a3 = p1.y * sw;
  float a4 = p2.x * sw, a5 = p2.y * sw, a6 = p3.x * sw, a7 = p3.y * sw;
  constexpr int D = 6;
  if (s < e) {
    int srcs[D];
    #pragma unroll
    for (int j = 0; j < D; ++j) {
      int idx = s + j;
      srcs[j] = csr[(idx < e) ? idx : (e - 1)];
    }
    int base = s;
    for (; base + D <= e; base += D) {           // full batches
      uint4 q[D];
      float wd[D];
      #pragma unroll
      for (int j = 0; j < D; ++j) q[j] = Hq[(size_t)srcs[j] * 16 + fl];
      #pragma unroll
      for (int j = 0; j < D; ++j) wd[j] = dis[srcs[j]];
      int ns[D];                                 // prefetch next batch srcs
      #pragma unroll
      for (int j = 0; j < D; ++j) {
        int idx = base + D + j;
        ns[j] = csr[(idx < e) ? idx : (e - 1)];
      }
      #pragma unroll
      for (int j = 0; j < D; ++j) {
        float w = wd[j] * d;
        float2 t;
        t = h2f(q[j].x); a0 = fmaf(w, t.x, a0); a1 = fmaf(w, t.y, a1);
        t = h2f(q[j].y); a2 = fmaf(w, t.x, a2); a3 = fmaf(w, t.y, a3);
        t = h2f(q[j].z); a4 = fmaf(w, t.x, a4); a5 = fmaf(w, t.y, a5);
        t = h2f(q[j].w); a6 = fmaf(w, t.x, a6); a7 = fmaf(w, t.y, a7);
      }
      #pragma unroll
      for (int j = 0; j < D; ++j) srcs[j] = ns[j];
    }
    if (base < e) {                              // masked tail batch
      uint4 q[D];
      float wd[D];
      #pragma unroll
      for (int j = 0; j < D; ++j) q[j] = Hq[(size_t)srcs[j] * 16 + fl];
      #pragma unroll
      for (int j = 0; j < D; ++j) wd[j] = dis[srcs[j]];
      #pragma unroll
      for (int j = 0; j < D; ++j) {
        float w = (base + j < e) ? wd[j] * d : 0.f;
        float2 t;
        t = h2f(q[j].x); a0 = fmaf(w, t.x, a0); a1 = fmaf(w, t.y, a1);
        t = h2f(q[j].y); a2 = fmaf(w, t.x, a2); a3 = fmaf(w, t.y, a3);
        t = h2f(q[j].z); a4 = fmaf(w, t.x, a4); a5 = fmaf(w, t.y, a5);
        t = h2f(q[j].w); a6 = fmaf(w, t.x, a6); a7 = fmaf(w, t.y, a7);
      }
    }
  }
  // +b1, relu, fp16 -> LDS row nb
  {
    const float4* Bq = (const float4*)bias;
    float4 b0 = Bq[fl * 2], b1v = Bq[fl * 2 + 1];
    f16x8 hrow;
    hrow[0] = (_Float16)fmaxf(a0 + b0.x, 0.f);
    hrow[1] = (_Float16)fmaxf(a1 + b0.y, 0.f);
    hrow[2] = (_Float16)fmaxf(a2 + b0.z, 0.f);
    hrow[3] = (_Float16)fmaxf(a3 + b0.w, 0.f);
    hrow[4] = (_Float16)fmaxf(a4 + b1v.x, 0.f);
    hrow[5] = (_Float16)fmaxf(a5 + b1v.y, 0.f);
    hrow[6] = (_Float16)fmaxf(a6 + b1v.z, 0.f);
    hrow[7] = (_Float16)fmaxf(a7 + b1v.w, 0.f);
    *(f16x8*)&Hs[nb * 136 + fl * 8] = hrow;
  }
  __syncthreads();

  // ---- stage B: 16x64 = (16x128) @ (128x64), wave w -> cols [w*16, +16) ----
  const int quad = lane >> 4, mrow = lane & 15;
  f32x4 acc = (f32x4){0.f, 0.f, 0.f, 0.f};
  const int c = wid * 16 + mrow;
  #pragma unroll
  for (int ko = 0; ko < 4; ++ko) {
    f16x8 avx = *(const f16x8*)&Hs[mrow * 136 + ko * 32 + quad * 8];
    f16x8 bv = *(const f16x8*)&Wts[c * 128 + (((ko * 4 + quad) ^ (c & 7)) << 3)];
    acc = __builtin_amdgcn_mfma_f32_16x16x32_f16(avx, bv, acc, 0, 0, 0);
  }

  __syncthreads();   // all waves done reading Hs; safe to alias
  #pragma unroll
  for (int r = 0; r < 4; ++r)
    Hs[(quad * 4 + r) * 136 + wid * 16 + mrow] = (_Float16)acc[r];
  __syncthreads();

  // contiguous stores: 128 f16x8 chunks (16 rows x 8), threads 0..127
  if (tid < 128) {
    int r = tid >> 3, ch = tid & 7;
    *(f16x8*)((_Float16*)H2 + ((size_t)blockIdx.x * 16 + r) * 64 + ch * 8) =
        *(const f16x8*)&Hs[r * 136 + ch * 8];
  }
}

// ---------------- aggregate 64 feats (+bias): per-edge dis norm ----------------
// 4 nodes/wave, 16 lanes/node, uint2 (4 feats)/lane; D=8 batches,
// batch-ahead csr prefetch.
__global__ __launch_bounds__(256) void k_agg64(const __half* __restrict__ H,
                                               const unsigned short* __restrict__ csr,
                                               const int* __restrict__ rowptr,
                                               const float* __restrict__ dis,
                                               const float* __restrict__ bias,
                                               float* __restrict__ Out, int n) {
  const int wid = threadIdx.x >> 6, lane = threadIdx.x & 63;
  const int sub = lane >> 4, fl = lane & 15;
  int v = blockIdx.x * 16 + wid * 4 + sub;
  if (v >= n) return;
  int s = rowptr[v], e = rowptr[v + 1];
  float d = dis[v];
  float sw = d * d;
  const uint2* Hq = (const uint2*)H;             // 16 uint2 per 128B row
  uint2 hv = Hq[(size_t)v * 16 + fl];
  float2 p0 = h2f(hv.x), p1 = h2f(hv.y);
  float a0 = p0.x * sw, a1 = p0.y * sw, a2 = p1.x * sw, a3 = p1.y * sw;
  constexpr int D = 8;
  if (s < e) {
    int srcs[D];
    #pragma unroll
    for (int j = 0; j < D; ++j) {
      int idx = s + j;
      srcs[j] = csr[(idx < e) ? idx : (e - 1)];
    }
    int base = s;
    for (; base + D <= e; base += D) {           // full batches
      uint2 q[D];
      float wd[D];
      #pragma unroll
      for (int j = 0; j < D; ++j) q[j] = Hq[(size_t)srcs[j] * 16 + fl];
      #pragma unroll
      for (int j = 0; j < D; ++j) wd[j] = dis[srcs[j]];
      int ns[D];                                 // prefetch next batch srcs
      #pragma unroll
      for (int j = 0; j < D; ++j) {
        int idx = base + D + j;
        ns[j] = csr[(idx < e) ? idx : (e - 1)];
      }
      #pragma unroll
      for (int j = 0; j < D; ++j) {
        float w = wd[j] * d;
        float2 t;
        t = h2f(q[j].x); a0 = fmaf(w, t.x, a0); a1 = fmaf(w, t.y, a1);
        t = h2f(q[j].y); a2 = fmaf(w, t.x, a2); a3 = fmaf(w, t.y, a3);
      }
      #pragma unroll
      for (int j = 0; j < D; ++j) srcs[j] = ns[j];
    }
    if (base < e) {                              // masked tail batch
      uint2 q[D];
      float wd[D];
      #pragma unroll
      for (int j = 0; j < D; ++j) q[j] = Hq[(size_t)srcs[j] * 16 + fl];
      #pragma unroll
      for (int j = 0; j < D; ++j) wd[j] = dis[srcs[j]];
      #pragma unroll
      for (int j = 0; j < D; ++j) {
        float w = (base + j < e) ? wd[j] * d : 0.f;
        float2 t;
        t = h2f(q[j].x); a0 = fmaf(w, t.x, a0); a1 = fmaf(w, t.y, a1);
        t = h2f(q[j].y); a2 = fmaf(w, t.x, a2); a3 = fmaf(w, t.y, a3);
      }
    }
  }
  const float4* Bq = (const float4*)bias;
  float4 b = Bq[fl];
  float4 o = make_float4(a0 + b.x, a1 + b.y, a2 + b.z, a3 + b.w);
  ((float4*)(Out + (size_t)v * 64))[fl] = o;
}

extern "C" void kernel_launch(void* const* d_in, const int* in_sizes, int n_in,
                              void* d_out, int out_size, void* d_ws, size_t ws_size,
                              hipStream_t stream) {
  const float* x  = (const float*)d_in[0];
  const int*   ei = (const int*)d_in[1];    // [2, E] row-major
  const int*   row = ei;                    // edge_index[0] (source)
  const int*   col = ei + Ne;               // edge_index[1] (dest / segment)
  const float* W1 = (const float*)d_in[2];
  const float* b1 = (const float*)d_in[3];
  const float* W2 = (const float*)d_in[4];
  const float* b2 = (const float*)d_in[5];
  float* out = (float*)d_out;

  char* ws = (char*)d_ws;
  size_t off = 0;
  auto alloc = [&](size_t bytes) -> void* {
    void* p = ws + off;
    off += (bytes + 255) & ~(size_t)255;
    return p;
  };
  int*    degi   = (int*)   alloc(Nn * sizeof(int));       // zeroed by k_prep
  int*    rowptr = (int*)   alloc((Nn + 1) * sizeof(int));
  float*  dis    = (float*) alloc(Nn * sizeof(float));
  int*    bstate = (int*)   alloc(64 * sizeof(int));       // zeroed by k_prep
  unsigned short* rank = (unsigned short*)alloc((size_t)Ne * sizeof(unsigned short)); // 1.6 MB
  unsigned short* csr  = (unsigned short*)alloc((size_t)Ne * sizeof(unsigned short)); // 1.6 MB
  __half* H1     = (__half*)alloc((size_t)Nn * 128 * sizeof(__half));  // 12.8 MB (unscaled)
  __half* H2     = (__half*)alloc((size_t)Nn * 64 * sizeof(__half));   // 6.4 MB (unscaled)
  _Float16* W1h  = (_Float16*)alloc(128 * 128 * sizeof(_Float16));     // 32 KB
  _Float16* W2h  = (_Float16*)alloc(64 * 128 * sizeof(_Float16));      // 16 KB

  const int NGB = (Nn + 15) / 16;           // 3125 agg blocks (16 nodes each)

  // 1) prep: degi=0, bstate=0, swizzled fp16 W images
  k_prep<<<51, 256, 0, stream>>>(W1, W2, W1h, W2h, degi, bstate);
  // 2) fused: H1 = fp16(x@W1) + degree count (hidden under GEMM)
  k_gemm32_count<<<GT32, 256, 0, stream>>>(x, W1h, H1, (const int2*)col,
                                           degi, (ushort2*)rank);
  // 3) single-dispatch lookback scan: rowptr + dis
  k_scan_lb<<<SCAN_B, 1024, 0, stream>>>(degi, rowptr, dis, bstate);
  // 4) CSR fill (no atomics)
  k_fill<<<E1B, 256, 0, stream>>>((const int2*)row, (const int2*)col, rowptr,
                                  (const ushort2*)rank, csr);
  // 5) fused: H2 = fp16( relu(agg(H1) + b1) @ W2 )
  k_agg128_gemm64<<<NGB, 256, 0, stream>>>(H1, csr, rowptr, dis, b1, W2h, H2, Nn);
  // 6) layer 2: out = agg(H2) + b2
  k_agg64<<<NGB, 256, 0, stream>>>(H2, csr, rowptr, dis, b2, out, Nn);
}